// Round 4
// baseline (366.693 us; speedup 1.0000x reference)
//
#include <hip/hip_runtime.h>
#include <hip/hip_bf16.h>

// Problem constants (B=8,S=4096,D=1024, A=16, C=8, dc=64, apc=2)
#define DIM 1024
#define NANCH 16
#define NCOMP 8
#define DC 64
#define DC2 128
#define EPS_LN 1e-5f
#define EPS_NORM 1e-12f

typedef __bf16 bf16x8 __attribute__((ext_vector_type(8)));
typedef __bf16 bf16x4 __attribute__((ext_vector_type(4)));
typedef float f32x4 __attribute__((ext_vector_type(4)));

// Fragment-chunk convention (verified by r3's AnB/W2B + kgemm epilogue):
//   chunk(t, ks) = 512 contiguous bf16 at base (t*16 + ks)*512
//   element (m, k) -> offset m*8 + ((k&31)>>3)*128 + (k&7)
// ds_read_b128 at base + lane*8 elems yields exactly the MFMA A/B operand.

__device__ __forceinline__ void gload16(const void* g, void* l) {
  __builtin_amdgcn_global_load_lds(
      (const __attribute__((address_space(1))) unsigned int*)g,
      (__attribute__((address_space(3))) unsigned int*)l, 16, 0, 0);
}

// ---------- Kernel 1 (prep, one launch): WpB | AnB | W2B -----------------
// blocks 0..63   : WpB[(jt*16+ks)*512 + ...] = Wp[k][n] (B-frag order, bf16)
// block  64      : AnB (anchor L2-normalize + B-frag order)
// blocks 65..320 : W2B (B-frag order per comp)
__global__ __launch_bounds__(256) void kprep(
    const float* __restrict__ Wp, const float* __restrict__ anchors,
    const float* __restrict__ W2,
    __hip_bfloat16* __restrict__ WpB, __hip_bfloat16* __restrict__ AnB,
    __hip_bfloat16* __restrict__ W2B) {
  int b = blockIdx.x, t = threadIdx.x;
  if (b < 64) {
    int jt = b, l15 = t & 15, ks = t >> 4;   // ks in [0,16)
    int n = jt * 16 + l15;
    size_t obase = (size_t)(jt * 16 + ks) * 512 + l15 * 8;
#pragma unroll
    for (int rr = 0; rr < 32; rr++) {
      int k = ks * 32 + rr;
      WpB[obase + ((rr >> 3) << 7) + (rr & 7)] =
          __float2bfloat16(Wp[(size_t)k * DIM + n]);
    }
  } else if (b == 64) {
    __shared__ float invn[16];
    int a = t >> 4, sub = t & 15;
    float ss = 0.f;
#pragma unroll 8
    for (int i = 0; i < 64; i++) {
      float v = anchors[a * DIM + sub * 64 + i];
      ss += v * v;
    }
#pragma unroll
    for (int off = 1; off < 16; off <<= 1) ss += __shfl_xor(ss, off);
    if (sub == 0) invn[a] = 1.f / fmaxf(sqrtf(ss), EPS_NORM);
    __syncthreads();
    for (int q = 0; q < 64; q++) {
      int o = t * 64 + q;
      int j = o & 7, lane = (o >> 3) & 63, ks = o >> 9;
      int e = ks * 32 + (lane >> 4) * 8 + j;
      int aa = lane & 15;
      AnB[o] = __float2bfloat16(anchors[aa * DIM + e] * invn[aa]);
    }
  } else {
    int id = (b - 65) * 256 + t;  // [0, 65536)
    int j = id & 7, lane = (id >> 3) & 63, ks = (id >> 9) & 3,
        nt = (id >> 11) & 3, k = id >> 13;
    int e = ks * 32 + (lane >> 4) * 8 + j;
    int n = nt * 16 + (lane & 15);
    W2B[id] = __float2bfloat16(W2[k * (DC2 * DC) + e * DC + n]);
  }
}

// ---------------- Kernel 2: 16 tokens/block -> Ys (frag-order bf16) ------
#define LDA_H 1032  // 1024 + 8 bf16 pad
__global__ __launch_bounds__(256) void ktoken(
    const float* __restrict__ x, const __hip_bfloat16* __restrict__ AnB,
    const float* __restrict__ ln_g, const float* __restrict__ ln_b,
    const float* __restrict__ W1, const float* __restrict__ b1,
    const __hip_bfloat16* __restrict__ W2B, const float* __restrict__ b2,
    const float* __restrict__ cg, const float* __restrict__ cb,
    __hip_bfloat16* __restrict__ Ys) {
  int t = threadIdx.x;
  int lane = t & 63, w = t >> 6;
  int l15 = lane & 15, quad = lane >> 4;
  int n0 = blockIdx.x * 16;

  __shared__ __hip_bfloat16 hu[16 * LDA_H];  // 33 KB: h, then u
  __shared__ float tri_s[16 * 16];           // [token][anchor]
  __shared__ float part[4 * 64 * 4];         // tri partial tiles

  // ---- Phase A: LN + l2norm, tokens w*4..w*4+3; float4-vectorized ----
  float4 gvv[4], bvv[4];
#pragma unroll
  for (int i = 0; i < 4; i++) {
    gvv[i] = ((const float4*)ln_g)[i * 64 + lane];
    bvv[i] = ((const float4*)ln_b)[i * 64 + lane];
  }
#pragma unroll
  for (int it = 0; it < 4; it++) {
    int tok = w * 4 + it;
    const float4* xr4 = (const float4*)(x + (size_t)(n0 + tok) * DIM);
    float4 xv[4];
    float s = 0.f, s2 = 0.f;
#pragma unroll
    for (int i = 0; i < 4; i++) {
      float4 v = xr4[i * 64 + lane];
      xv[i] = v;
      s += v.x + v.y + v.z + v.w;
      s2 += v.x * v.x + v.y * v.y + v.z * v.z + v.w * v.w;
    }
#pragma unroll
    for (int off = 32; off; off >>= 1) { s += __shfl_xor(s, off); s2 += __shfl_xor(s2, off); }
    float mu = s * (1.f / DIM);
    float rstd = rsqrtf(s2 * (1.f / DIM) - mu * mu + EPS_LN);
    float ss = 0.f;
#pragma unroll
    for (int i = 0; i < 4; i++) {
      float4 g = gvv[i], bb = bvv[i], v = xv[i];
      v.x = (v.x - mu) * rstd * g.x + bb.x; v.y = (v.y - mu) * rstd * g.y + bb.y;
      v.z = (v.z - mu) * rstd * g.z + bb.z; v.w = (v.w - mu) * rstd * g.w + bb.w;
      xv[i] = v;
      ss += v.x * v.x + v.y * v.y + v.z * v.z + v.w * v.w;
    }
#pragma unroll
    for (int off = 32; off; off >>= 1) ss += __shfl_xor(ss, off);
    float inv = 1.f / fmaxf(sqrtf(ss), EPS_NORM);
#pragma unroll
    for (int i = 0; i < 4; i++) {
      bf16x4 hb;
      hb[0] = (__bf16)(xv[i].x * inv); hb[1] = (__bf16)(xv[i].y * inv);
      hb[2] = (__bf16)(xv[i].z * inv); hb[3] = (__bf16)(xv[i].w * inv);
      *(bf16x4*)(&hu[tok * LDA_H + i * 256 + lane * 4]) = hb;
    }
  }
  __syncthreads();

  // ---- Phase B: tri[m][a] = 1 - h@AnT via MFMA over K=1024 ----
  {
    f32x4 tacc = {0.f, 0.f, 0.f, 0.f};
#pragma unroll
    for (int ks = w * 8; ks < w * 8 + 8; ks++) {
      bf16x8 afr = *(const bf16x8*)(&hu[l15 * LDA_H + ks * 32 + quad * 8]);
      bf16x8 bfr = *(const bf16x8*)(&AnB[ks * 512 + lane * 8]);
      tacc = __builtin_amdgcn_mfma_f32_16x16x32_bf16(afr, bfr, tacc, 0, 0, 0);
    }
    *(f32x4*)(&part[(w * 64 + lane) * 4]) = tacc;
  }
  __syncthreads();
  {
    int ln = t & 63, rg = t >> 6;
    float v = part[(0 * 64 + ln) * 4 + rg] + part[(1 * 64 + ln) * 4 + rg] +
              part[(2 * 64 + ln) * 4 + rg] + part[(3 * 64 + ln) * 4 + rg];
    int m = (ln >> 4) * 4 + rg, a = ln & 15;
    tri_s[m * 16 + a] = 1.f - v;
  }
  __syncthreads();

  // ---- Phase C: u = relu(tri0*W1a + tri1*W1b + b1)^2 -> hu ----
  {
    float w1a[4], w1b[4], b1v[4];
#pragma unroll
    for (int i = 0; i < 4; i++) {
      int idx = i * 256 + t, k = idx >> 7, e = idx & 127;
      w1a[i] = W1[k * 256 + e];
      w1b[i] = W1[k * 256 + 128 + e];
      b1v[i] = b1[idx];
    }
#pragma unroll
    for (int tok = 0; tok < 16; tok++) {
#pragma unroll
      for (int i = 0; i < 4; i++) {
        int idx = i * 256 + t, k = idx >> 7;
        float uu = tri_s[tok * 16 + k] * w1a[i] +
                   tri_s[tok * 16 + 8 + k] * w1b[i] + b1v[i];
        uu = fmaxf(uu, 0.f);
        hu[tok * LDA_H + idx] = __float2bfloat16(uu * uu);
      }
    }
  }
  __syncthreads();

  // ---- Phase D: y = u@W2 + b2, LN(dc=64), write in frag-chunk order ----
#pragma unroll
  for (int kc = 0; kc < 2; kc++) {
    int k = w * 2 + kc;
    bf16x8 afr[4];
#pragma unroll
    for (int ks = 0; ks < 4; ks++)
      afr[ks] = *(const bf16x8*)(&hu[l15 * LDA_H + k * 128 + ks * 32 + quad * 8]);
    f32x4 acc[4] = {{0,0,0,0},{0,0,0,0},{0,0,0,0},{0,0,0,0}};
#pragma unroll
    for (int nt = 0; nt < 4; nt++) {
#pragma unroll
      for (int ks = 0; ks < 4; ks++) {
        bf16x8 bfr = *(const bf16x8*)(&W2B[(size_t)(((k * 4 + nt) * 4 + ks)) * 512 + lane * 8]);
        acc[nt] = __builtin_amdgcn_mfma_f32_16x16x32_bf16(afr[ks], bfr, acc[nt], 0, 0, 0);
      }
    }
    float vals[4][4], s1[4] = {0,0,0,0}, s2[4] = {0,0,0,0};
#pragma unroll
    for (int nt = 0; nt < 4; nt++) {
      float b2v = b2[k * 64 + nt * 16 + l15];
#pragma unroll
      for (int r = 0; r < 4; r++) {
        float v = acc[nt][r] + b2v;
        vals[nt][r] = v; s1[r] += v; s2[r] += v * v;
      }
    }
#pragma unroll
    for (int r = 0; r < 4; r++) {
#pragma unroll
      for (int off = 1; off < 16; off <<= 1) {
        s1[r] += __shfl_xor(s1[r], off);
        s2[r] += __shfl_xor(s2[r], off);
      }
    }
#pragma unroll
    for (int r = 0; r < 4; r++) {
      float mu = s1[r] * (1.f / DC);
      float rs = rsqrtf(s2[r] * (1.f / DC) - mu * mu + EPS_LN);
      int m = quad * 4 + r;  // token within this 16-token group
#pragma unroll
      for (int nt = 0; nt < 4; nt++) {
        int d = nt * 16 + l15;
        float yn = (vals[nt][r] - mu) * rs * cg[k * 64 + d] + cb[k * 64 + d];
        int kk = k * 64 + d;            // global col in [0,512)
        int ks = kk >> 5, km = kk & 31;
        Ys[(size_t)(blockIdx.x * 16 + ks) * 512 + m * 8 + ((km >> 3) << 7) + (km & 7)]
            = __float2bfloat16(yn);
      }
    }
  }
}

// ---------------- Kernel 3: out = x + sig(gate)*(Y @ Wp + bp) -----------
// m97-style: frag-ordered chunks staged via global_load_lds width=16;
// all ds_read_b128 at base + lane*16 (conflict-free). 128x128 tile, BK=64.
__global__ __launch_bounds__(256) void kgemm(
    const __hip_bfloat16* __restrict__ Ys, const __hip_bfloat16* __restrict__ WpB,
    const float* __restrict__ x, const float* __restrict__ bp,
    const float* __restrict__ gate, float* __restrict__ out) {
  __shared__ alignas(16) __hip_bfloat16 As[16 * 512];  // 16 KB
  __shared__ alignas(16) __hip_bfloat16 Bs[16 * 512];  // 16 KB
  int t = threadIdx.x, lane = t & 63, wid = t >> 6;
  int bm = blockIdx.x, bj = blockIdx.y;
  int l15 = lane & 15, quad = lane >> 4;

  f32x4 acc[4][4] = {};

  for (int k0 = 0; k0 < 512; k0 += 64) {
    int ks0 = k0 >> 5;
#pragma unroll
    for (int it = 0; it < 4; it++) {
      int c = wid * 4 + it;            // chunk 0..15
      int tl = c >> 1, s = c & 1;
      gload16(Ys + ((size_t)(bm * 8 + tl) * 16 + ks0 + s) * 512 + lane * 8,
              &As[c * 512]);
      gload16(WpB + ((size_t)(bj * 8 + tl) * 16 + ks0 + s) * 512 + lane * 8,
              &Bs[c * 512]);
    }
    __syncthreads();
#pragma unroll
    for (int s = 0; s < 2; s++) {
      bf16x8 af[4], bfr[4];
#pragma unroll
      for (int i = 0; i < 4; i++) {
        af[i]  = *(const bf16x8*)(&As[((((wid >> 1) * 4 + i) << 1) + s) * 512 + lane * 8]);
        bfr[i] = *(const bf16x8*)(&Bs[((((wid & 1) * 4 + i) << 1) + s) * 512 + lane * 8]);
      }
#pragma unroll
      for (int i = 0; i < 4; i++)
#pragma unroll
        for (int j = 0; j < 4; j++)
          acc[i][j] = __builtin_amdgcn_mfma_f32_16x16x32_bf16(af[i], bfr[j], acc[i][j], 0, 0, 0);
    }
    __syncthreads();
  }

  int wm = (wid >> 1) * 64, wj = (wid & 1) * 64;
  float sg[4], bpv[4];
#pragma unroll
  for (int j = 0; j < 4; j++) {
    int gc = bj * 128 + wj + j * 16 + l15;
    sg[j] = 1.f / (1.f + expf(-gate[gc]));
    bpv[j] = bp[gc];
  }
#pragma unroll
  for (int i = 0; i < 4; i++) {
#pragma unroll
    for (int j = 0; j < 4; j++) {
      int gc = bj * 128 + wj + j * 16 + l15;
#pragma unroll
      for (int r = 0; r < 4; r++) {
        int gr = bm * 128 + wm + i * 16 + quad * 4 + r;   // D row=(lane>>4)*4+reg
        size_t idx = (size_t)gr * DIM + gc;
        out[idx] = x[idx] + sg[j] * (acc[i][j][r] + bpv[j]);
      }
    }
  }
}

extern "C" void kernel_launch(void* const* d_in, const int* in_sizes, int n_in,
                              void* d_out, int out_size, void* d_ws, size_t ws_size,
                              hipStream_t stream) {
  const float* x       = (const float*)d_in[0];
  const float* anchors = (const float*)d_in[1];
  const float* ln_g    = (const float*)d_in[2];
  const float* ln_b    = (const float*)d_in[3];
  const float* W1      = (const float*)d_in[4];
  const float* b1      = (const float*)d_in[5];
  const float* W2      = (const float*)d_in[6];
  const float* b2      = (const float*)d_in[7];
  const float* cg      = (const float*)d_in[8];
  const float* cb      = (const float*)d_in[9];
  const float* Wp      = (const float*)d_in[10];
  const float* bp      = (const float*)d_in[11];
  const float* gate    = (const float*)d_in[12];

  int N = in_sizes[0] / DIM;  // 32768 tokens

  char* w = (char*)d_ws;
  size_t off = 0;
  __hip_bfloat16* AnB = (__hip_bfloat16*)(w + off);  off += 32 << 10;    // 32 KB
  __hip_bfloat16* WpB = (__hip_bfloat16*)(w + off);  off += 1 << 20;     // 1 MB
  __hip_bfloat16* W2B = (__hip_bfloat16*)(w + off);  off += 128 << 10;   // 128 KB
  __hip_bfloat16* Ys  = (__hip_bfloat16*)(w + off);                      // 32 MB

  kprep<<<321, 256, 0, stream>>>(Wp, anchors, W2, WpB, AnB, W2B);
  ktoken<<<N / 16, 256, 0, stream>>>(x, AnB, ln_g, ln_b, W1, b1, W2B, b2, cg, cb, Ys);
  kgemm<<<dim3(N / 128, DIM / 128), 256, 0, stream>>>(Ys, WpB, x, bp, gate,
                                                      (float*)d_out);
}